// Round 4
// baseline (44.708 us; speedup 1.0000x reference)
//
#include <hip/hip_runtime.h>

// LIF recurrence: x [T=256, B=32, H=64, W=64] f32 -> spikes same shape.
// Independent across the 131072 spatial elements; sequential over T.
//
// R1: 44.4us @ float2/thread, UNROLL 8. R3 (nt stores): 43.1us, neutral —
// FETCH still 64 MiB (L3 retains half of x regardless), WRITE 128 MiB.
// Actual HBM = 192 MiB => 32us floor at 6.3 TB/s; at 43us we're only at
// 4.7 TB/s actual => latency/MLP-bound, not BW-bound (Occupancy 9%,
// in-flight 16 KB/CU vs ~900cy HBM latency).
// R4: 1 f32/thread (131072 threads = 8 waves/CU, 2x TLP) + UNROLL 16
// (64 B in flight per thread) => 32 KB/CU in flight. Keep nt stores.
//
// Numerics: reference (numpy/XLA f32) does NOT contract mul+add into FMA.
// Spikes are a hard threshold (v_dec > 1.0): a differently-rounded FMA can
// flip a spike. All recurrence math uses __fmul_rn/__fadd_rn to pin the
// exact f32 op sequence of the reference.

#define T_STEPS 256
#define UNROLL 16

__global__ __launch_bounds__(256) void lif_kernel(
    const float* __restrict__ x, float* __restrict__ out,
    const float* __restrict__ tsi_p, const float* __restrict__ tmi_p,
    int n)
{
    int idx = blockIdx.x * blockDim.x + threadIdx.x;
    if (idx >= n) return;

    const float tmi = *tmi_p;
    const float tsi = *tsi_p;
    // a = DT * tau_mem_inv ; b = 1 - DT * tau_syn_inv  (exact ref op order)
    const float a = __fmul_rn(0.001f, tmi);
    const float b = __fsub_rn(1.0f, __fmul_rn(0.001f, tsi));

    const float* xp = x + idx;
    float*       op = out + idx;

    float v = 0.f, i = 0.f;
    float cur[UNROLL], nxt[UNROLL];

#pragma unroll
    for (int j = 0; j < UNROLL; ++j) cur[j] = xp[(size_t)j * n];
    xp += (size_t)UNROLL * n;

    for (int t = 0; t < T_STEPS; t += UNROLL) {
        // prefetch next chunk while computing current (double buffer)
        if (t + UNROLL < T_STEPS) {
#pragma unroll
            for (int j = 0; j < UNROLL; ++j) nxt[j] = xp[(size_t)j * n];
            xp += (size_t)UNROLL * n;
        }

        float z[UNROLL];
#pragma unroll
        for (int j = 0; j < UNROLL; ++j) {
            // v_dec = v + a * ((0 - v) + i)   [no FMA]
            float vd = __fadd_rn(v, __fmul_rn(a, __fadd_rn(i, -v)));
            // z = (v_dec - V_TH > 0)  <=>  v_dec > 1.0f in f32
            z[j] = vd > 1.0f ? 1.0f : 0.0f;
            // v_new = (1-z)*v_dec + z*0  => select
            v = vd > 1.0f ? 0.0f : vd;
            // i_new = i * b + x_t   [no FMA: mul then add]
            i = __fadd_rn(__fmul_rn(i, b), cur[j]);
        }

        // Non-temporal stores: output is write-once/never-read.
#pragma unroll
        for (int j = 0; j < UNROLL; ++j)
            __builtin_nontemporal_store(z[j], &op[(size_t)j * n]);
        op += (size_t)UNROLL * n;

#pragma unroll
        for (int j = 0; j < UNROLL; ++j) cur[j] = nxt[j];
    }
}

extern "C" void kernel_launch(void* const* d_in, const int* in_sizes, int n_in,
                              void* d_out, int out_size, void* d_ws, size_t ws_size,
                              hipStream_t stream) {
    const float* x   = (const float*)d_in[0];
    const float* tsi = (const float*)d_in[1];
    const float* tmi = (const float*)d_in[2];
    float* out = (float*)d_out;

    int total = in_sizes[0];          // T * B * H * W = 33554432
    int n  = total / T_STEPS;         // 131072 elements per timestep

    dim3 block(256);
    dim3 grid((n + block.x - 1) / block.x);   // 512 blocks, 8 waves/CU
    hipLaunchKernelGGL(lif_kernel, grid, block, 0, stream,
                       x, out, tsi, tmi, n);
}